// Round 5
// baseline (1360.366 us; speedup 1.0000x reference)
//
#include <hip/hip_runtime.h>
#include <math.h>

#define IMH 480
#define IMW 640
#define HW (IMH*IMW)
#define KPT 512
#define DESC 256
#define CAP 32768
#define NMSR 3

// ---------------------------------------------------------------- MT19937
// Replicates np.random.RandomState(42).uniform(-8,8,(256,4)) -> round -> int.
__global__ void init_offsets_kernel(int* __restrict__ offs) {
  __shared__ unsigned int mt[624];
  __shared__ unsigned int old[624];
  __shared__ unsigned int tp[2496];   // 4 generations x 624 tempered draws
  const int tid = threadIdx.x;
  if (tid == 0) {
    unsigned int s = 42u;
    for (int i = 0; i < 624; ++i) { mt[i] = s; s = 1812433253u * (s ^ (s >> 30)) + (unsigned)i + 1u; }
  }
  __syncthreads();
  for (int g = 0; g < 4; ++g) {
    for (int k = tid; k < 624; k += 256) old[k] = mt[k];
    __syncthreads();
    for (int k = tid; k < 227; k += 256) {
      unsigned int y = (old[k] & 0x80000000u) | (old[k + 1] & 0x7fffffffu);
      mt[k] = old[k + 397] ^ (y >> 1) ^ ((y & 1u) ? 0x9908b0dfu : 0u);
    }
    __syncthreads();
    for (int k = 227 + tid; k < 454; k += 256) {
      unsigned int y = (old[k] & 0x80000000u) | (old[k + 1] & 0x7fffffffu);
      mt[k] = mt[k - 227] ^ (y >> 1) ^ ((y & 1u) ? 0x9908b0dfu : 0u);
    }
    __syncthreads();
    for (int k = 454 + tid; k < 623; k += 256) {
      unsigned int y = (old[k] & 0x80000000u) | (old[k + 1] & 0x7fffffffu);
      mt[k] = mt[k - 227] ^ (y >> 1) ^ ((y & 1u) ? 0x9908b0dfu : 0u);
    }
    __syncthreads();
    if (tid == 0) {
      unsigned int y = (old[623] & 0x80000000u) | (mt[0] & 0x7fffffffu);
      mt[623] = mt[396] ^ (y >> 1) ^ ((y & 1u) ? 0x9908b0dfu : 0u);
    }
    __syncthreads();
    for (int k = tid; k < 624; k += 256) {
      unsigned int y = mt[k];
      y ^= (y >> 11);
      y ^= (y << 7)  & 0x9d2c5680u;
      y ^= (y << 15) & 0xefc60000u;
      y ^= (y >> 18);
      tp[g * 624 + k] = y;
    }
    __syncthreads();
  }
  for (int i = tid; i < 1024; i += 256) {
    unsigned int a = tp[2 * i] >> 5, b = tp[2 * i + 1] >> 6;
    double r = ((double)a * 67108864.0 + (double)b) / 9007199254740992.0;
    offs[i] = (int)rint(-8.0 + 16.0 * r);
  }
}

__global__ void init_misc_kernel(int* __restrict__ counts, float* __restrict__ sel_val,
                                 int* __restrict__ sel_idx, float* __restrict__ u,
                                 float* __restrict__ v, int* __restrict__ bar,
                                 int* __restrict__ rank_arr) {
  int t = blockIdx.x * blockDim.x + threadIdx.x;
  if (t < 2) counts[t] = 0;
  if (t == 2) *bar = 0;
  if (t < 2 * KPT) { sel_val[t] = 0.f; sel_idx[t] = -1; }
  if (t < 513) { u[t] = 0.f; v[t] = 0.f; }
  for (int i = t; i < 2 * CAP; i += 16384) rank_arr[i] = 0;
}

// ---------------------------------------------------------------- detector (LDS-tiled)
#define DTW 64
#define DTH 16
__global__ void detector_kernel(const float* __restrict__ img0, const float* __restrict__ img1,
                                float* __restrict__ scores, float* __restrict__ smooth) {
  const int b = blockIdx.z;
  const int x0 = blockIdx.x * DTW;
  const int y0 = blockIdx.y * DTH;
  const float* __restrict__ img = b ? img1 : img0;
  __shared__ float tile[(DTH + 4) * (DTW + 4)];   // 20x68, zero-filled OOB
  const int tid = threadIdx.x;
  for (int i = tid; i < (DTH + 4) * (DTW + 4); i += 256) {
    int ly = i / (DTW + 4), lx = i - ly * (DTW + 4);
    int gy = y0 + ly - 2, gx = x0 + lx - 2;
    tile[i] = (gy >= 0 && gy < IMH && gx >= 0 && gx < IMW) ? img[gy * IMW + gx] : 0.f;
  }
  __syncthreads();
  for (int i = tid; i < DTH * DTW; i += 256) {
    int ly = i / DTW, lx = i - ly * DTW;
    int y = y0 + ly, x = x0 + lx;
    float a[5][5];
    #pragma unroll
    for (int ii = 0; ii < 5; ++ii)
      #pragma unroll
      for (int jj = 0; jj < 5; ++jj)
        a[ii][jj] = tile[(ly + ii) * (DTW + 4) + lx + jj];
    float sm = 0.f;
    #pragma unroll
    for (int ii = 0; ii < 5; ++ii)
      #pragma unroll
      for (int jj = 0; jj < 5; ++jj) sm += a[ii][jj];
    smooth[b * HW + y * IMW + x] = sm * (1.f / 25.f);

    float sxx = 0.f, syy = 0.f, sxy = 0.f;
    #pragma unroll
    for (int cy = -1; cy <= 1; ++cy) {
      #pragma unroll
      for (int cx = -1; cx <= 1; ++cx) {
        int yy = y + cy, xx = x + cx;
        if (yy < 0 || yy >= IMH || xx < 0 || xx >= IMW) continue;
        int iu = cy + 2, iv = cx + 2;
        float ix = (a[iu - 1][iv + 1] - a[iu - 1][iv - 1])
                 + 2.f * (a[iu][iv + 1] - a[iu][iv - 1])
                 + (a[iu + 1][iv + 1] - a[iu + 1][iv - 1]);
        float iy = (a[iu + 1][iv - 1] + 2.f * a[iu + 1][iv] + a[iu + 1][iv + 1])
                 - (a[iu - 1][iv - 1] + 2.f * a[iu - 1][iv] + a[iu - 1][iv + 1]);
        sxx += ix * ix; syy += iy * iy; sxy += ix * iy;
      }
    }
    sxx *= (1.f / 9.f); syy *= (1.f / 9.f); sxy *= (1.f / 9.f);
    float half_tr = 0.5f * (sxx + syy);
    float hd = 0.5f * (sxx - syy);
    scores[b * HW + y * IMW + x] = half_tr - sqrtf(hd * hd + sxy * sxy + 1e-12f);
  }
}

// ---------------------------------------------------------------- NMS (separable 7x7 max, LDS-tiled) + compact
#define NTW 64
#define NTH 32
__global__ void nms_cand_kernel(const float* __restrict__ scores,
                                float* __restrict__ cand_val, int* __restrict__ cand_idx,
                                int* __restrict__ counts) {
  const int b = blockIdx.z;
  const int x0 = blockIdx.x * NTW;
  const int y0 = blockIdx.y * NTH;
  const float* __restrict__ sc = scores + b * HW;
  __shared__ float sm[(NTH + 6) * (NTW + 6)];
  __shared__ float hm[(NTH + 6) * NTW];
  const int tid = threadIdx.x;
  for (int i = tid; i < (NTH + 6) * (NTW + 6); i += 256) {
    int ly = i / (NTW + 6), lx = i - ly * (NTW + 6);
    int gy = y0 + ly - 3, gx = x0 + lx - 3;
    sm[i] = (gy >= 0 && gy < IMH && gx >= 0 && gx < IMW) ? sc[gy * IMW + gx] : -INFINITY;
  }
  __syncthreads();
  for (int i = tid; i < (NTH + 6) * NTW; i += 256) {
    int ly = i / NTW, lx = i - ly * NTW;
    const float* r = sm + ly * (NTW + 6) + lx;
    float m = r[0];
    #pragma unroll
    for (int d = 1; d < 7; ++d) m = fmaxf(m, r[d]);
    hm[i] = m;
  }
  __syncthreads();
  for (int i = tid; i < NTH * NTW; i += 256) {
    int ly = i / NTW, lx = i - ly * NTW;
    float s = sm[(ly + 3) * (NTW + 6) + lx + 3];
    if (s <= 0.f) continue;
    float m = hm[ly * NTW + lx];
    #pragma unroll
    for (int d = 1; d < 7; ++d) m = fmaxf(m, hm[(ly + d) * NTW + lx]);
    if (s >= m - 1e-7f) {
      int gy = y0 + ly, gx = x0 + lx;
      int slot = atomicAdd(&counts[b], 1);
      if (slot < CAP) {
        cand_val[b * CAP + slot] = s;
        cand_idx[b * CAP + slot] = gy * IMW + gx;
      }
    }
  }
}

// ---------------------------------------------------------------- top-512: 2D-tiled rank count
// key = (float bits << 32) | ~idx  — positive floats order as uints, so
// key_j > key_i  <=>  (vj > vi) || (vj == vi && ij < ii). Keys unique.
__global__ void rank_partial_kernel(const float* __restrict__ cand_val,
                                    const int* __restrict__ cand_idx,
                                    const int* __restrict__ counts,
                                    int* __restrict__ rank_arr) {
  int b = blockIdx.z;
  int n = counts[b]; if (n > CAP) n = CAP;
  if ((int)(blockIdx.x * 256) >= n || (int)(blockIdx.y * 256) >= n) return;
  const float* cv = cand_val + b * CAP;
  const int* ci = cand_idx + b * CAP;
  int i = blockIdx.x * 256 + threadIdx.x;
  int j = blockIdx.y * 256 + threadIdx.x;
  __shared__ unsigned long long sk[256];
  sk[threadIdx.x] = (j < n)
      ? (((unsigned long long)__float_as_uint(cv[j]) << 32) | (0xFFFFFFFFu - (unsigned)ci[j]))
      : 0ull;   // 0 never outranks a real key (values > 0)
  __syncthreads();
  if (i >= n) return;
  unsigned long long ki = ((unsigned long long)__float_as_uint(cv[i]) << 32)
                        | (0xFFFFFFFFu - (unsigned)ci[i]);
  int r = 0;
  #pragma unroll 8
  for (int t = 0; t < 256; ++t) r += (sk[t] > ki) ? 1 : 0;
  atomicAdd(&rank_arr[b * CAP + i], r);
}

__global__ void scatter_topk_kernel(const float* __restrict__ cand_val,
                                    const int* __restrict__ cand_idx,
                                    const int* __restrict__ counts,
                                    const int* __restrict__ rank_arr,
                                    float* __restrict__ sel_val, int* __restrict__ sel_idx) {
  int b = blockIdx.y;
  int n = counts[b]; if (n > CAP) n = CAP;
  int i = blockIdx.x * 256 + threadIdx.x;
  if (i >= n) return;
  int r = rank_arr[b * CAP + i];
  if (r < KPT) {
    sel_val[b * KPT + r] = cand_val[b * CAP + i];
    sel_idx[b * KPT + r] = cand_idx[b * CAP + i];
  }
}

// ---------------------------------------------------------------- kp out + BAD desc + L2 norm
__global__ void kp_desc_kernel(const float* __restrict__ sel_val, const int* __restrict__ sel_idx,
                               const float* __restrict__ smooth, const int* __restrict__ offs,
                               float* __restrict__ desc, float* __restrict__ a2_out,
                               float* __restrict__ out) {
  int blk = blockIdx.x;          // 0..1023
  int b = blk >> 9;
  int k = blk & 511;
  int lane = threadIdx.x;        // 0..63 (one wave)
  float val = sel_val[b * KPT + k];
  int idx = sel_idx[b * KPT + k];
  bool valid = (val > 0.f) && (idx >= 0);
  int y = 0, x = 0;
  if (valid) { y = idx / IMW; x = idx - y * IMW; }
  const float* sm = smooth + b * HW;
  float d[4];
  #pragma unroll
  for (int t2 = 0; t2 < 4; ++t2) {
    int pp = (lane << 2) + t2;
    int oy1 = offs[4 * pp + 0], ox1 = offs[4 * pp + 1];
    int oy2 = offs[4 * pp + 2], ox2 = offs[4 * pp + 3];
    int ya = min(max(y + oy1, 0), IMH - 1), xa = min(max(x + ox1, 0), IMW - 1);
    int yb = min(max(y + oy2, 0), IMH - 1), xb = min(max(x + ox2, 0), IMW - 1);
    float v2 = sm[ya * IMW + xa] - sm[yb * IMW + xb];
    d[t2] = valid ? v2 : 0.f;
  }
  float ss = d[0] * d[0] + d[1] * d[1] + d[2] * d[2] + d[3] * d[3];
  #pragma unroll
  for (int off = 32; off; off >>= 1) ss += __shfl_down(ss, off);
  ss = __shfl(ss, 0);
  float scale = 1.f / (sqrtf(ss) + 1e-8f);
  float* dd = desc + (size_t)(b * KPT + k) * DESC;
  #pragma unroll
  for (int t2 = 0; t2 < 4; ++t2) dd[(lane << 2) + t2] = d[t2] * scale;
  if (lane == 0) {
    a2_out[b * KPT + k] = ss * scale * scale;
    float* kp = out + b * (2 * KPT) + k * 2;
    kp[0] = valid ? (float)y : -1.f;
    kp[1] = valid ? (float)x : -1.f;
  }
}

// ---------------------------------------------------------------- Z = sim with dustbin
__global__ void similarity_kernel(const float* __restrict__ desc, const float* __restrict__ a2,
                                  float* __restrict__ Z) {
  int t = blockIdx.x * blockDim.x + threadIdx.x;
  if (t >= 513 * 513) return;
  int k = t / 513;
  int l = t - k * 513;
  float z;
  if (k == KPT || l == KPT) {
    z = 1.0f;   // UNUSED / EPSILON
  } else {
    const float* d1 = desc + (size_t)k * DESC;
    const float* d2 = desc + (size_t)(KPT + l) * DESC;
    float dot = 0.f;
    #pragma unroll 8
    for (int d = 0; d < DESC; ++d) dot += d1[d] * d2[d];
    float sq = a2[k] + a2[KPT + l] - 2.f * dot;
    sq = fmaxf(sq, 0.f);
    z = -sqrtf(sq + 1e-12f);
  }
  Z[t] = z;
}

// ---------------------------------------------------------------- fused sinkhorn (513 blocks, manual grid barrier)
__device__ __forceinline__ float blk_reduce_max(float val, float* red) {
  #pragma unroll
  for (int off = 32; off; off >>= 1) val = fmaxf(val, __shfl_down(val, off));
  if ((threadIdx.x & 63) == 0) red[threadIdx.x >> 6] = val;
  __syncthreads();
  float r = fmaxf(fmaxf(red[0], red[1]), fmaxf(red[2], red[3]));
  __syncthreads();
  return r;
}

__device__ __forceinline__ float blk_reduce_sum(float val, float* red) {
  #pragma unroll
  for (int off = 32; off; off >>= 1) val += __shfl_down(val, off);
  if ((threadIdx.x & 63) == 0) red[threadIdx.x >> 6] = val;
  __syncthreads();
  float r = (red[0] + red[1]) + (red[2] + red[3]);
  __syncthreads();
  return r;
}

#define NBLK 513
__device__ __forceinline__ void grid_bar(int* bar, int gen) {
  __syncthreads();
  if (threadIdx.x == 0) {
    __hip_atomic_fetch_add(bar, 1, __ATOMIC_ACQ_REL, __HIP_MEMORY_SCOPE_AGENT);
    int target = NBLK * (gen + 1);
    int guard = 0;
    while (__hip_atomic_load(bar, __ATOMIC_ACQUIRE, __HIP_MEMORY_SCOPE_AGENT) < target) {
      __builtin_amdgcn_s_sleep(2);
      if (++guard > (1 << 20)) break;   // hang insurance; never expected
    }
  }
  __syncthreads();
}

// Block k owns row k AND column k of Z in registers (513 = 256 + 256 + 1).
// 513 blocks x 4 waves << 2048-block residency capacity -> barrier is safe.
__global__ __launch_bounds__(256) void sinkhorn_fused_kernel(
    const float* __restrict__ Z, float* __restrict__ u, float* __restrict__ v,
    int* __restrict__ bar, float* __restrict__ out) {
  const int k = blockIdx.x;        // 0..512
  const int tid = threadIdx.x;
  __shared__ float red[4];
  const size_t ro = (size_t)k * 513;
  float r0 = Z[ro + tid];
  float r1 = Z[ro + 256 + tid];
  float r2 = (tid == 0) ? Z[ro + 512] : -INFINITY;
  float c0 = Z[(size_t)tid * 513 + k];
  float c1 = Z[(size_t)(256 + tid) * 513 + k];
  float c2 = (tid == 0) ? Z[(size_t)512 * 513 + k] : -INFINITY;
  const float norm = -logf(1024.0f);
  const float lmu = (k == KPT) ? (logf(512.0f) + norm) : norm;
  float uk = 0.f;
  int gen = 0;
  for (int it = 0; it < 20; ++it) {
    // u-phase: u[k] = lmu - lse_l(Zrow + v)
    float v0 = __hip_atomic_load(&v[tid], __ATOMIC_RELAXED, __HIP_MEMORY_SCOPE_AGENT);
    float v1 = __hip_atomic_load(&v[256 + tid], __ATOMIC_RELAXED, __HIP_MEMORY_SCOPE_AGENT);
    float v2 = (tid == 0) ? __hip_atomic_load(&v[512], __ATOMIC_RELAXED, __HIP_MEMORY_SCOPE_AGENT)
                          : -INFINITY;
    float a0 = r0 + v0, a1 = r1 + v1, a2 = r2 + v2;
    float m = blk_reduce_max(fmaxf(fmaxf(a0, a1), a2), red);
    float s = blk_reduce_sum(expf(a0 - m) + expf(a1 - m) + expf(a2 - m), red);
    uk = lmu - (logf(s) + m);
    if (tid == 0) __hip_atomic_store(&u[k], uk, __ATOMIC_RELEASE, __HIP_MEMORY_SCOPE_AGENT);
    grid_bar(bar, gen++);
    // v-phase: v[k] = lnu - lse_kk(Zcol + u)
    float u0 = __hip_atomic_load(&u[tid], __ATOMIC_RELAXED, __HIP_MEMORY_SCOPE_AGENT);
    float u1 = __hip_atomic_load(&u[256 + tid], __ATOMIC_RELAXED, __HIP_MEMORY_SCOPE_AGENT);
    float u2 = (tid == 0) ? __hip_atomic_load(&u[512], __ATOMIC_RELAXED, __HIP_MEMORY_SCOPE_AGENT)
                          : -INFINITY;
    float b0 = c0 + u0, b1 = c1 + u1, b2 = c2 + u2;
    m = blk_reduce_max(fmaxf(fmaxf(b0, b1), b2), red);
    s = blk_reduce_sum(expf(b0 - m) + expf(b1 - m) + expf(b2 - m), red);
    float vk = lmu - (logf(s) + m);
    if (tid == 0) __hip_atomic_store(&v[k], vk, __ATOMIC_RELEASE, __HIP_MEMORY_SCOPE_AGENT);
    grid_bar(bar, gen++);
  }
  // probs: exp(Z + u + v - norm), row k
  float v0 = __hip_atomic_load(&v[tid], __ATOMIC_RELAXED, __HIP_MEMORY_SCOPE_AGENT);
  float v1 = __hip_atomic_load(&v[256 + tid], __ATOMIC_RELAXED, __HIP_MEMORY_SCOPE_AGENT);
  float* o = out + ro;
  o[tid] = expf(r0 + uk + v0 - norm);
  o[256 + tid] = expf(r1 + uk + v1 - norm);
  if (tid == 0) {
    float v2 = __hip_atomic_load(&v[512], __ATOMIC_RELAXED, __HIP_MEMORY_SCOPE_AGENT);
    o[512] = expf(r2 + uk + v2 - norm);
  }
}

// ---------------------------------------------------------------- launch
extern "C" void kernel_launch(void* const* d_in, const int* in_sizes, int n_in,
                              void* d_out, int out_size, void* d_ws, size_t ws_size,
                              hipStream_t stream) {
  const float* img1 = (const float*)d_in[0];
  const float* img2 = (const float*)d_in[1];
  float* out = (float*)d_out;

  char* p = (char*)d_ws;
  auto alloc = [&](size_t bytes) { char* r = p; p += (bytes + 255) & ~(size_t)255; return r; };
  int*   offs     = (int*)alloc(1024 * 4);
  int*   counts   = (int*)alloc(2 * 4);
  int*   bar      = (int*)alloc(4);
  float* sel_val  = (float*)alloc(2 * KPT * 4);
  int*   sel_idx  = (int*)alloc(2 * KPT * 4);
  float* uu       = (float*)alloc(513 * 4);
  float* vv       = (float*)alloc(513 * 4);
  float* a2       = (float*)alloc(2 * KPT * 4);
  float* scores   = (float*)alloc((size_t)2 * HW * 4);
  float* smooth   = (float*)alloc((size_t)2 * HW * 4);
  float* cand_val = (float*)alloc((size_t)2 * CAP * 4);
  int*   cand_idx = (int*)alloc((size_t)2 * CAP * 4);
  int*   rank_arr = (int*)alloc((size_t)2 * CAP * 4);
  float* desc     = (float*)alloc((size_t)2 * KPT * DESC * 4);
  float* Z        = (float*)alloc((size_t)513 * 513 * 4);

  init_offsets_kernel<<<1, 256, 0, stream>>>(offs);
  init_misc_kernel<<<64, 256, 0, stream>>>(counts, sel_val, sel_idx, uu, vv, bar, rank_arr);
  detector_kernel<<<dim3(IMW / DTW, IMH / DTH, 2), 256, 0, stream>>>(img1, img2, scores, smooth);
  nms_cand_kernel<<<dim3(IMW / NTW, IMH / NTH, 2), 256, 0, stream>>>(scores, cand_val, cand_idx, counts);
  rank_partial_kernel<<<dim3(CAP / 256, CAP / 256, 2), 256, 0, stream>>>(cand_val, cand_idx, counts, rank_arr);
  scatter_topk_kernel<<<dim3(CAP / 256, 2), 256, 0, stream>>>(cand_val, cand_idx, counts, rank_arr, sel_val, sel_idx);
  kp_desc_kernel<<<1024, 64, 0, stream>>>(sel_val, sel_idx, smooth, offs, desc, a2, out);
  similarity_kernel<<<(513 * 513 + 255) / 256, 256, 0, stream>>>(desc, a2, Z);
  sinkhorn_fused_kernel<<<NBLK, 256, 0, stream>>>(Z, uu, vv, bar, out + 2048);
}

// Round 6
// 545.719 us; speedup vs baseline: 2.4928x; 2.4928x over previous
//
#include <hip/hip_runtime.h>
#include <math.h>

#define IMH 480
#define IMW 640
#define HW (IMH*IMW)
#define KPT 512
#define DESC 256
#define CAP 32768
#define NMSR 3

// ---------------------------------------------------------------- MT19937
// Replicates np.random.RandomState(42).uniform(-8,8,(256,4)) -> round -> int.
__global__ void init_offsets_kernel(int* __restrict__ offs) {
  __shared__ unsigned int mt[624];
  __shared__ unsigned int old[624];
  __shared__ unsigned int tp[2496];   // 4 generations x 624 tempered draws
  const int tid = threadIdx.x;
  if (tid == 0) {
    unsigned int s = 42u;
    for (int i = 0; i < 624; ++i) { mt[i] = s; s = 1812433253u * (s ^ (s >> 30)) + (unsigned)i + 1u; }
  }
  __syncthreads();
  for (int g = 0; g < 4; ++g) {
    for (int k = tid; k < 624; k += 256) old[k] = mt[k];
    __syncthreads();
    for (int k = tid; k < 227; k += 256) {
      unsigned int y = (old[k] & 0x80000000u) | (old[k + 1] & 0x7fffffffu);
      mt[k] = old[k + 397] ^ (y >> 1) ^ ((y & 1u) ? 0x9908b0dfu : 0u);
    }
    __syncthreads();
    for (int k = 227 + tid; k < 454; k += 256) {
      unsigned int y = (old[k] & 0x80000000u) | (old[k + 1] & 0x7fffffffu);
      mt[k] = mt[k - 227] ^ (y >> 1) ^ ((y & 1u) ? 0x9908b0dfu : 0u);
    }
    __syncthreads();
    for (int k = 454 + tid; k < 623; k += 256) {
      unsigned int y = (old[k] & 0x80000000u) | (old[k + 1] & 0x7fffffffu);
      mt[k] = mt[k - 227] ^ (y >> 1) ^ ((y & 1u) ? 0x9908b0dfu : 0u);
    }
    __syncthreads();
    if (tid == 0) {
      unsigned int y = (old[623] & 0x80000000u) | (mt[0] & 0x7fffffffu);
      mt[623] = mt[396] ^ (y >> 1) ^ ((y & 1u) ? 0x9908b0dfu : 0u);
    }
    __syncthreads();
    for (int k = tid; k < 624; k += 256) {
      unsigned int y = mt[k];
      y ^= (y >> 11);
      y ^= (y << 7)  & 0x9d2c5680u;
      y ^= (y << 15) & 0xefc60000u;
      y ^= (y >> 18);
      tp[g * 624 + k] = y;
    }
    __syncthreads();
  }
  for (int i = tid; i < 1024; i += 256) {
    unsigned int a = tp[2 * i] >> 5, b = tp[2 * i + 1] >> 6;
    double r = ((double)a * 67108864.0 + (double)b) / 9007199254740992.0;
    offs[i] = (int)rint(-8.0 + 16.0 * r);
  }
}

__global__ void init_misc_kernel(int* __restrict__ counts, float* __restrict__ sel_val,
                                 int* __restrict__ sel_idx, float* __restrict__ u,
                                 float* __restrict__ v, int* __restrict__ bar,
                                 int* __restrict__ rank_arr) {
  int t = blockIdx.x * blockDim.x + threadIdx.x;
  if (t < 2) counts[t] = 0;
  if (t == 2) *bar = 0;
  if (t < 2 * KPT) { sel_val[t] = 0.f; sel_idx[t] = -1; }
  if (t < 513) { u[t] = 0.f; v[t] = 0.f; }
  for (int i = t; i < 2 * CAP; i += 16384) rank_arr[i] = 0;
}

// ---------------------------------------------------------------- detector (LDS-tiled)
#define DTW 64
#define DTH 16
__global__ void detector_kernel(const float* __restrict__ img0, const float* __restrict__ img1,
                                float* __restrict__ scores, float* __restrict__ smooth) {
  const int b = blockIdx.z;
  const int x0 = blockIdx.x * DTW;
  const int y0 = blockIdx.y * DTH;
  const float* __restrict__ img = b ? img1 : img0;
  __shared__ float tile[(DTH + 4) * (DTW + 4)];
  const int tid = threadIdx.x;
  for (int i = tid; i < (DTH + 4) * (DTW + 4); i += 256) {
    int ly = i / (DTW + 4), lx = i - ly * (DTW + 4);
    int gy = y0 + ly - 2, gx = x0 + lx - 2;
    tile[i] = (gy >= 0 && gy < IMH && gx >= 0 && gx < IMW) ? img[gy * IMW + gx] : 0.f;
  }
  __syncthreads();
  for (int i = tid; i < DTH * DTW; i += 256) {
    int ly = i / DTW, lx = i - ly * DTW;
    int y = y0 + ly, x = x0 + lx;
    float a[5][5];
    #pragma unroll
    for (int ii = 0; ii < 5; ++ii)
      #pragma unroll
      for (int jj = 0; jj < 5; ++jj)
        a[ii][jj] = tile[(ly + ii) * (DTW + 4) + lx + jj];
    float sm = 0.f;
    #pragma unroll
    for (int ii = 0; ii < 5; ++ii)
      #pragma unroll
      for (int jj = 0; jj < 5; ++jj) sm += a[ii][jj];
    smooth[b * HW + y * IMW + x] = sm * (1.f / 25.f);

    float sxx = 0.f, syy = 0.f, sxy = 0.f;
    #pragma unroll
    for (int cy = -1; cy <= 1; ++cy) {
      #pragma unroll
      for (int cx = -1; cx <= 1; ++cx) {
        int yy = y + cy, xx = x + cx;
        if (yy < 0 || yy >= IMH || xx < 0 || xx >= IMW) continue;
        int iu = cy + 2, iv = cx + 2;
        float ix = (a[iu - 1][iv + 1] - a[iu - 1][iv - 1])
                 + 2.f * (a[iu][iv + 1] - a[iu][iv - 1])
                 + (a[iu + 1][iv + 1] - a[iu + 1][iv - 1]);
        float iy = (a[iu + 1][iv - 1] + 2.f * a[iu + 1][iv] + a[iu + 1][iv + 1])
                 - (a[iu - 1][iv - 1] + 2.f * a[iu - 1][iv] + a[iu - 1][iv + 1]);
        sxx += ix * ix; syy += iy * iy; sxy += ix * iy;
      }
    }
    sxx *= (1.f / 9.f); syy *= (1.f / 9.f); sxy *= (1.f / 9.f);
    float half_tr = 0.5f * (sxx + syy);
    float hd = 0.5f * (sxx - syy);
    scores[b * HW + y * IMW + x] = half_tr - sqrtf(hd * hd + sxy * sxy + 1e-12f);
  }
}

// ---------------------------------------------------------------- NMS (separable 7x7 max, LDS-tiled) + compact
#define NTW 64
#define NTH 32
__global__ void nms_cand_kernel(const float* __restrict__ scores,
                                float* __restrict__ cand_val, int* __restrict__ cand_idx,
                                int* __restrict__ counts) {
  const int b = blockIdx.z;
  const int x0 = blockIdx.x * NTW;
  const int y0 = blockIdx.y * NTH;
  const float* __restrict__ sc = scores + b * HW;
  __shared__ float sm[(NTH + 6) * (NTW + 6)];
  __shared__ float hm[(NTH + 6) * NTW];
  const int tid = threadIdx.x;
  for (int i = tid; i < (NTH + 6) * (NTW + 6); i += 256) {
    int ly = i / (NTW + 6), lx = i - ly * (NTW + 6);
    int gy = y0 + ly - 3, gx = x0 + lx - 3;
    sm[i] = (gy >= 0 && gy < IMH && gx >= 0 && gx < IMW) ? sc[gy * IMW + gx] : -INFINITY;
  }
  __syncthreads();
  for (int i = tid; i < (NTH + 6) * NTW; i += 256) {
    int ly = i / NTW, lx = i - ly * NTW;
    const float* r = sm + ly * (NTW + 6) + lx;
    float m = r[0];
    #pragma unroll
    for (int d = 1; d < 7; ++d) m = fmaxf(m, r[d]);
    hm[i] = m;
  }
  __syncthreads();
  for (int i = tid; i < NTH * NTW; i += 256) {
    int ly = i / NTW, lx = i - ly * NTW;
    float s = sm[(ly + 3) * (NTW + 6) + lx + 3];
    if (s <= 0.f) continue;
    float m = hm[ly * NTW + lx];
    #pragma unroll
    for (int d = 1; d < 7; ++d) m = fmaxf(m, hm[(ly + d) * NTW + lx]);
    if (s >= m - 1e-7f) {
      int gy = y0 + ly, gx = x0 + lx;
      int slot = atomicAdd(&counts[b], 1);
      if (slot < CAP) {
        cand_val[b * CAP + slot] = s;
        cand_idx[b * CAP + slot] = gy * IMW + gx;
      }
    }
  }
}

// ---------------------------------------------------------------- top-512: 2D-tiled rank count
__global__ void rank_partial_kernel(const float* __restrict__ cand_val,
                                    const int* __restrict__ cand_idx,
                                    const int* __restrict__ counts,
                                    int* __restrict__ rank_arr) {
  int b = blockIdx.z;
  int n = counts[b]; if (n > CAP) n = CAP;
  if ((int)(blockIdx.x * 256) >= n || (int)(blockIdx.y * 256) >= n) return;
  const float* cv = cand_val + b * CAP;
  const int* ci = cand_idx + b * CAP;
  int i = blockIdx.x * 256 + threadIdx.x;
  int j = blockIdx.y * 256 + threadIdx.x;
  __shared__ unsigned long long sk[256];
  sk[threadIdx.x] = (j < n)
      ? (((unsigned long long)__float_as_uint(cv[j]) << 32) | (0xFFFFFFFFu - (unsigned)ci[j]))
      : 0ull;
  __syncthreads();
  if (i >= n) return;
  unsigned long long ki = ((unsigned long long)__float_as_uint(cv[i]) << 32)
                        | (0xFFFFFFFFu - (unsigned)ci[i]);
  int r = 0;
  #pragma unroll 8
  for (int t = 0; t < 256; ++t) r += (sk[t] > ki) ? 1 : 0;
  atomicAdd(&rank_arr[b * CAP + i], r);
}

__global__ void scatter_topk_kernel(const float* __restrict__ cand_val,
                                    const int* __restrict__ cand_idx,
                                    const int* __restrict__ counts,
                                    const int* __restrict__ rank_arr,
                                    float* __restrict__ sel_val, int* __restrict__ sel_idx) {
  int b = blockIdx.y;
  int n = counts[b]; if (n > CAP) n = CAP;
  int i = blockIdx.x * 256 + threadIdx.x;
  if (i >= n) return;
  int r = rank_arr[b * CAP + i];
  if (r < KPT) {
    sel_val[b * KPT + r] = cand_val[b * CAP + i];
    sel_idx[b * KPT + r] = cand_idx[b * CAP + i];
  }
}

// ---------------------------------------------------------------- kp out + BAD desc + L2 norm
__global__ void kp_desc_kernel(const float* __restrict__ sel_val, const int* __restrict__ sel_idx,
                               const float* __restrict__ smooth, const int* __restrict__ offs,
                               float* __restrict__ desc, float* __restrict__ a2_out,
                               float* __restrict__ out) {
  int blk = blockIdx.x;
  int b = blk >> 9;
  int k = blk & 511;
  int lane = threadIdx.x;
  float val = sel_val[b * KPT + k];
  int idx = sel_idx[b * KPT + k];
  bool valid = (val > 0.f) && (idx >= 0);
  int y = 0, x = 0;
  if (valid) { y = idx / IMW; x = idx - y * IMW; }
  const float* sm = smooth + b * HW;
  float d[4];
  #pragma unroll
  for (int t2 = 0; t2 < 4; ++t2) {
    int pp = (lane << 2) + t2;
    int oy1 = offs[4 * pp + 0], ox1 = offs[4 * pp + 1];
    int oy2 = offs[4 * pp + 2], ox2 = offs[4 * pp + 3];
    int ya = min(max(y + oy1, 0), IMH - 1), xa = min(max(x + ox1, 0), IMW - 1);
    int yb = min(max(y + oy2, 0), IMH - 1), xb = min(max(x + ox2, 0), IMW - 1);
    float v2 = sm[ya * IMW + xa] - sm[yb * IMW + xb];
    d[t2] = valid ? v2 : 0.f;
  }
  float ss = d[0] * d[0] + d[1] * d[1] + d[2] * d[2] + d[3] * d[3];
  #pragma unroll
  for (int off = 32; off; off >>= 1) ss += __shfl_down(ss, off);
  ss = __shfl(ss, 0);
  float scale = 1.f / (sqrtf(ss) + 1e-8f);
  float* dd = desc + (size_t)(b * KPT + k) * DESC;
  #pragma unroll
  for (int t2 = 0; t2 < 4; ++t2) dd[(lane << 2) + t2] = d[t2] * scale;
  if (lane == 0) {
    a2_out[b * KPT + k] = ss * scale * scale;
    float* kp = out + b * (2 * KPT) + k * 2;
    kp[0] = valid ? (float)y : -1.f;
    kp[1] = valid ? (float)x : -1.f;
  }
}

// ---------------------------------------------------------------- Z = sim with dustbin
__global__ void similarity_kernel(const float* __restrict__ desc, const float* __restrict__ a2,
                                  float* __restrict__ Z) {
  int t = blockIdx.x * blockDim.x + threadIdx.x;
  if (t >= 513 * 513) return;
  int k = t / 513;
  int l = t - k * 513;
  float z;
  if (k == KPT || l == KPT) {
    z = 1.0f;
  } else {
    const float* d1 = desc + (size_t)k * DESC;
    const float* d2 = desc + (size_t)(KPT + l) * DESC;
    float dot = 0.f;
    #pragma unroll 8
    for (int d = 0; d < DESC; ++d) dot += d1[d] * d2[d];
    float sq = a2[k] + a2[KPT + l] - 2.f * dot;
    sq = fmaxf(sq, 0.f);
    z = -sqrtf(sq + 1e-12f);
  }
  Z[t] = z;
}

// ---------------------------------------------------------------- fused sinkhorn
// 16 blocks x 1024 threads. Block g owns rows/cols [r0,r1). Barrier = 16
// device-scope RMWs (vs 513 in R4 — that was 25 us/barrier of serialized
// cross-XCD RMW). Spin is RELAXED (no per-poll cache invalidate); one
// ACQUIRE on exit publishes u/v.
#define SNB 16
__device__ __forceinline__ void grid_bar16(int* bar, int target) {
  __syncthreads();
  if (threadIdx.x == 0) {
    __hip_atomic_fetch_add(bar, 1, __ATOMIC_RELEASE, __HIP_MEMORY_SCOPE_AGENT);
    int guard = 0;
    while (__hip_atomic_load(bar, __ATOMIC_RELAXED, __HIP_MEMORY_SCOPE_AGENT) < target) {
      __builtin_amdgcn_s_sleep(4);
      if (++guard > (1 << 22)) break;   // hang insurance; never expected
    }
    (void)__hip_atomic_load(bar, __ATOMIC_ACQUIRE, __HIP_MEMORY_SCOPE_AGENT);
  }
  __syncthreads();
}

__global__ __launch_bounds__(1024) void sinkhorn_fused_kernel(
    const float* __restrict__ Z, float* __restrict__ u, float* __restrict__ v,
    int* __restrict__ bar, float* __restrict__ out) {
  const int g = blockIdx.x;
  const int tid = threadIdx.x;
  const int wave = tid >> 6;
  const int lane = tid & 63;
  const int r0 = (g * 513) / SNB;
  const int r1 = ((g + 1) * 513) / SNB;
  __shared__ float sh[513];     // staged u or v (phase-alternating)
  const float norm = -logf(1024.0f);
  const float lmu_bin = logf(512.0f) + norm;
  float uk_reg[4];
  int target = 0;
  for (int it = 0; it < 20; ++it) {
    // ---- u-phase: u[r] = lmu - log(sum_l exp(Z[r][l] + v[l]))
    for (int i = tid; i < 513; i += 1024)
      sh[i] = __hip_atomic_load(&v[i], __ATOMIC_RELAXED, __HIP_MEMORY_SCOPE_AGENT);
    __syncthreads();
    int ri = 0;
    for (int r = r0 + wave; r < r1; r += 16, ++ri) {
      const float* zr = Z + (size_t)r * 513;
      float s = 0.f;
      for (int idx = lane; idx < 513; idx += 64) s += expf(zr[idx] + sh[idx]);
      #pragma unroll
      for (int off = 32; off; off >>= 1) s += __shfl_xor(s, off);
      float uk = ((r == KPT) ? lmu_bin : norm) - logf(s);
      uk_reg[ri] = uk;
      if (lane == 0) u[r] = uk;
    }
    target += SNB; grid_bar16(bar, target);
    // ---- v-phase: v[c] = lnu - log(sum_k exp(Z[k][c] + u[k]))
    for (int i = tid; i < 513; i += 1024)
      sh[i] = __hip_atomic_load(&u[i], __ATOMIC_RELAXED, __HIP_MEMORY_SCOPE_AGENT);
    __syncthreads();
    for (int c = r0 + wave; c < r1; c += 16) {
      float s = 0.f;
      for (int k = lane; k < 513; k += 64) s += expf(Z[(size_t)k * 513 + c] + sh[k]);
      #pragma unroll
      for (int off = 32; off; off >>= 1) s += __shfl_xor(s, off);
      if (lane == 0) v[c] = ((c == KPT) ? lmu_bin : norm) - logf(s);
    }
    target += SNB; grid_bar16(bar, target);
  }
  // ---- probs: out[r][l] = exp(Z[r][l] + u[r] + v[l] - norm)
  for (int i = tid; i < 513; i += 1024)
    sh[i] = __hip_atomic_load(&v[i], __ATOMIC_RELAXED, __HIP_MEMORY_SCOPE_AGENT);
  __syncthreads();
  int ri = 0;
  for (int r = r0 + wave; r < r1; r += 16, ++ri) {
    const float* zr = Z + (size_t)r * 513;
    float* o = out + (size_t)r * 513;
    float uk = uk_reg[ri];
    for (int idx = lane; idx < 513; idx += 64)
      o[idx] = expf(zr[idx] + uk + sh[idx] - norm);
  }
}

// ---------------------------------------------------------------- launch
extern "C" void kernel_launch(void* const* d_in, const int* in_sizes, int n_in,
                              void* d_out, int out_size, void* d_ws, size_t ws_size,
                              hipStream_t stream) {
  const float* img1 = (const float*)d_in[0];
  const float* img2 = (const float*)d_in[1];
  float* out = (float*)d_out;

  char* p = (char*)d_ws;
  auto alloc = [&](size_t bytes) { char* r = p; p += (bytes + 255) & ~(size_t)255; return r; };
  int*   offs     = (int*)alloc(1024 * 4);
  int*   counts   = (int*)alloc(2 * 4);
  int*   bar      = (int*)alloc(4);
  float* sel_val  = (float*)alloc(2 * KPT * 4);
  int*   sel_idx  = (int*)alloc(2 * KPT * 4);
  float* uu       = (float*)alloc(513 * 4);
  float* vv       = (float*)alloc(513 * 4);
  float* a2       = (float*)alloc(2 * KPT * 4);
  float* scores   = (float*)alloc((size_t)2 * HW * 4);
  float* smooth   = (float*)alloc((size_t)2 * HW * 4);
  float* cand_val = (float*)alloc((size_t)2 * CAP * 4);
  int*   cand_idx = (int*)alloc((size_t)2 * CAP * 4);
  int*   rank_arr = (int*)alloc((size_t)2 * CAP * 4);
  float* desc     = (float*)alloc((size_t)2 * KPT * DESC * 4);
  float* Z        = (float*)alloc((size_t)513 * 513 * 4);

  init_offsets_kernel<<<1, 256, 0, stream>>>(offs);
  init_misc_kernel<<<64, 256, 0, stream>>>(counts, sel_val, sel_idx, uu, vv, bar, rank_arr);
  detector_kernel<<<dim3(IMW / DTW, IMH / DTH, 2), 256, 0, stream>>>(img1, img2, scores, smooth);
  nms_cand_kernel<<<dim3(IMW / NTW, IMH / NTH, 2), 256, 0, stream>>>(scores, cand_val, cand_idx, counts);
  rank_partial_kernel<<<dim3(CAP / 256, CAP / 256, 2), 256, 0, stream>>>(cand_val, cand_idx, counts, rank_arr);
  scatter_topk_kernel<<<dim3(CAP / 256, 2), 256, 0, stream>>>(cand_val, cand_idx, counts, rank_arr, sel_val, sel_idx);
  kp_desc_kernel<<<1024, 64, 0, stream>>>(sel_val, sel_idx, smooth, offs, desc, a2, out);
  similarity_kernel<<<(513 * 513 + 255) / 256, 256, 0, stream>>>(desc, a2, Z);
  sinkhorn_fused_kernel<<<SNB, 1024, 0, stream>>>(Z, uu, vv, bar, out + 2048);
}